// Round 17
// baseline (46.991 us; speedup 1.0000x reference)
//
#include <hip/hip_runtime.h>
#include <hip/hip_bf16.h>

#define BATCH 4096
#define DIM   512
#define NLBL  512
#define BIGF  1e4f
#define MARGIN 1.0f

#define BM 256        // tile (rows = cols) -- halves panel traffic vs 128
#define BK 32         // bf16 elems per K-step
#define NT (BATCH/BM) // 16
#define NPAIR (NT*(NT+1)/2)  // 136 = 8*17 (XCD-bijective)
#define KITERS (DIM/BK)      // 16

// Tiled layout: HiT[tileR128][chunk][128][32] bf16; 8KB contiguous panels.
#define PANEL_E 4096
#define TILE_E  65536

using f32x4  = __attribute__((ext_vector_type(4))) float;
using bf16x8 = __attribute__((ext_vector_type(8))) short;

// ---- compile-time pair table: row-major triangle enumeration (16x16) ----
struct PairTab { unsigned char bi[NPAIR]; unsigned char bj[NPAIR]; };
constexpr PairTab make_tab() {
    PairTab t{};
    int idx = 0;
    for (int i = 0; i < NT; ++i)
        for (int j = i; j < NT; ++j) {
            t.bi[idx] = (unsigned char)i;
            t.bj[idx] = (unsigned char)j;
            ++idx;
        }
    return t;
}
__device__ constexpr PairTab PT = make_tab();

__device__ __forceinline__ unsigned short f2bf(float x) {
    __hip_bfloat16 h = __float2bfloat16(x);
    return *reinterpret_cast<unsigned short*>(&h);
}

#define GLOAD16(gp, lp) \
    __builtin_amdgcn_global_load_lds((const __attribute__((address_space(1))) void*)(gp), \
                                     (__attribute__((address_space(3))) void*)(lp), 16, 0, 0)

// ---------------- kernel 1: row L2-normalize -> bf16 TILED layout (+ hp/hn init) ----------------
__global__ __launch_bounds__(256) void normalize_k(const float* __restrict__ emb,
                                                   unsigned short* __restrict__ HiT,
                                                   unsigned* __restrict__ hp,
                                                   unsigned* __restrict__ hn) {
    int wave = threadIdx.x >> 6;
    int lane = threadIdx.x & 63;
    int row  = blockIdx.x * 4 + wave;
    const float4* src = (const float4*)(emb + (size_t)row * DIM);
    float4 v0 = src[lane * 2];
    float4 v1 = src[lane * 2 + 1];
    float ss = v0.x*v0.x + v0.y*v0.y + v0.z*v0.z + v0.w*v0.w
             + v1.x*v1.x + v1.y*v1.y + v1.z*v1.z + v1.w*v1.w;
    #pragma unroll
    for (int off = 1; off < 64; off <<= 1) ss += __shfl_xor(ss, off);
    float scale = 1.0f / fmaxf(sqrtf(ss), 1e-12f);
    bf16x8 o;
    o[0] = (short)f2bf(v0.x * scale);
    o[1] = (short)f2bf(v0.y * scale);
    o[2] = (short)f2bf(v0.z * scale);
    o[3] = (short)f2bf(v0.w * scale);
    o[4] = (short)f2bf(v1.x * scale);
    o[5] = (short)f2bf(v1.y * scale);
    o[6] = (short)f2bf(v1.z * scale);
    o[7] = (short)f2bf(v1.w * scale);
    size_t off = (size_t)(row >> 7) * TILE_E + (size_t)(lane >> 2) * PANEL_E
               + (size_t)(row & 127) * 32 + (lane & 3) * 8;
    *(bf16x8*)(HiT + off) = o;
    if (lane == 0) {
        hp[row] = 0u;
        hn[row] = __float_as_uint(BIGF);
    }
}

// ---------------- kernel 2: fused bf16 MFMA sim + batch-hard mining, 256^2 tiles ----------------
// 8 waves (2x4), each wave a 128x64 sub-tile (8x4 fragments). Triple-buffered
// LDS, depth-3 counted-vmcnt pipeline (solo block per CU -> deeper prefetch).
// Panel traffic: 136 x 512KB = 69.6MB (half of the 128-tile version).
__global__ __launch_bounds__(512, 2) void mine_k(const unsigned short* __restrict__ HiT,
                                                 const int* __restrict__ lab,
                                                 unsigned* __restrict__ hp,
                                                 unsigned* __restrict__ hn) {
    __shared__ __attribute__((aligned(16))) unsigned short As[3][BM * BK]; // 48 KB
    __shared__ __attribute__((aligned(16))) unsigned short Bs[3][BM * BK]; // 48 KB
    __shared__ float rowp[4][BM], rown[4][BM];                             // 8 KB
    __shared__ float colp[2][BM], coln[2][BM];                             // 4 KB

    int orig = (int)blockIdx.x;
    int p = (orig & 7) * (NPAIR / 8) + (orig >> 3);   // 136 = 8*17, bijective
    const int bi = PT.bi[p];
    const int bj = PT.bj[p];
    const int i0 = bi * BM;
    const int j0 = bj * BM;

    const int tid  = threadIdx.x;
    const int w    = tid >> 6;      // wave 0..7
    const int lane = tid & 63;
    const int wr   = w >> 2;        // 0..1 : 128-row half
    const int wc   = w & 3;         // 0..3 : 64-col quarter
    const int l15  = lane & 15;
    const int lhi  = lane >> 4;     // 0..3 : 16B k-chunk within 64B row

    f32x4 acc[8][4] = {};
    const char* HiB = (const char*)HiT;

    // stage one 256x32 K-chunk of A and B; per wave 2 segs each (16 rows x 64B
    // = 1KB contiguous per GLOAD16 in the tiled layout).
    auto STAGE = [&](int buf, int t) {
        const int rrel = lane >> 2;                   // 0..15
        #pragma unroll
        for (int s = 0; s < 2; ++s) {
            const int r16 = (w * 2 + s) * 16;         // 0..240, multiple of 16
            const int rowl = r16 + rrel;              // block-local row
            const int sc  = (lane & 3) ^ ((rowl >> 1) & 3);
            const size_t pa = ((size_t)((i0 >> 7) * 16 + (r16 >> 7) * 16 + t)) * (PANEL_E * 2);
            const size_t pb = ((size_t)((j0 >> 7) * 16 + (r16 >> 7) * 16 + t)) * (PANEL_E * 2);
            const int soff = ((rowl & 127)) * 64 + (sc << 4);
            GLOAD16(HiB + pa + soff, (char*)As[buf] + r16 * 64);
            GLOAD16(HiB + pb + soff, (char*)Bs[buf] + r16 * 64);
        }
    };
    auto COMPUTE = [&](int buf) {
        bf16x8 a[8], b[4];
        #pragma unroll
        for (int m = 0; m < 8; ++m) {
            int row = wr * 128 + m * 16 + l15;
            int cp  = lhi ^ ((row >> 1) & 3);
            a[m] = *(const bf16x8*)((const char*)As[buf] + row * 64 + (cp << 4));
        }
        #pragma unroll
        for (int n = 0; n < 4; ++n) {
            int row = wc * 64 + n * 16 + l15;
            int cp  = lhi ^ ((row >> 1) & 3);
            b[n] = *(const bf16x8*)((const char*)Bs[buf] + row * 64 + (cp << 4));
        }
        #pragma unroll
        for (int m = 0; m < 8; ++m)
            #pragma unroll
            for (int n = 0; n < 4; ++n)
                acc[m][n] = __builtin_amdgcn_mfma_f32_16x16x32_bf16(a[m], b[n], acc[m][n], 0, 0, 0);
    };

    // ---- depth-3 counted-vmcnt triple-buffer pipeline ----
    STAGE(0, 0);
    STAGE(1, 1);
    STAGE(2, 2);      // 12 loads in flight per wave
    #pragma unroll
    for (int t = 0; t < KITERS; ++t) {
        const int cur = t % 3;
        if (t <= KITERS - 3) {
            asm volatile("s_waitcnt vmcnt(8)" ::: "memory");  // stage t landed; t+1,t+2 in flight
        } else if (t == KITERS - 2) {
            asm volatile("s_waitcnt vmcnt(4)" ::: "memory");
        } else {
            asm volatile("s_waitcnt vmcnt(0)" ::: "memory");
        }
        __builtin_amdgcn_sched_barrier(0);
        __builtin_amdgcn_s_barrier();      // buf cur fully written (all waves)
        COMPUTE(cur);
        __builtin_amdgcn_sched_barrier(0);
        __builtin_amdgcn_s_barrier();      // all waves done reading buf cur
        if (t + 3 < KITERS) STAGE(cur, t + 3);
    }

    // ---- labels ----
    int lj[4];
    #pragma unroll
    for (int n = 0; n < 4; ++n) lj[n] = lab[j0 + wc * 64 + n * 16 + l15];
    int li[32];
    #pragma unroll
    for (int m = 0; m < 8; ++m)
        #pragma unroll
        for (int r = 0; r < 4; ++r)
            li[m * 4 + r] = lab[i0 + wr * 128 + m * 16 + lhi * 4 + r];

    // ---- epilogue ----
    // C[i][j]: i = i0 + wr*128 + m*16 + lhi*4 + r ; j = j0 + wc*64 + n*16 + l15
    #pragma unroll
    for (int m = 0; m < 8; ++m) {
        #pragma unroll
        for (int r = 0; r < 4; ++r) {
            int i   = i0 + wr * 128 + m * 16 + lhi * 4 + r;
            int lir = li[m * 4 + r];
            float pm = 0.0f, nm = BIGF;
            #pragma unroll
            for (int n = 0; n < 4; ++n) {
                float dist = fmaxf(1.0f - acc[m][n][r], 0.0f);
                int j = j0 + wc * 64 + n * 16 + l15;
                if (lir == lj[n]) {
                    if (i != j) pm = fmaxf(pm, dist);
                } else {
                    nm = fminf(nm, dist);
                }
            }
            #pragma unroll
            for (int off = 1; off < 16; off <<= 1) {
                pm = fmaxf(pm, __shfl_xor(pm, off));
                nm = fminf(nm, __shfl_xor(nm, off));
            }
            if (l15 == 0) {
                int loc = wr * 128 + m * 16 + lhi * 4 + r;
                rowp[wc][loc] = pm;
                rown[wc][loc] = nm;
            }
        }
    }

    #pragma unroll
    for (int n = 0; n < 4; ++n) {
        int j   = j0 + wc * 64 + n * 16 + l15;
        int ljn = lj[n];
        float cp = 0.0f, cn = BIGF;
        #pragma unroll
        for (int m = 0; m < 8; ++m) {
            #pragma unroll
            for (int r = 0; r < 4; ++r) {
                float dist = fmaxf(1.0f - acc[m][n][r], 0.0f);
                int i = i0 + wr * 128 + m * 16 + lhi * 4 + r;
                if (li[m * 4 + r] == ljn) {
                    if (i != j) cp = fmaxf(cp, dist);
                } else {
                    cn = fminf(cn, dist);
                }
            }
        }
        #pragma unroll
        for (int off = 16; off < 64; off <<= 1) {
            cp = fmaxf(cp, __shfl_xor(cp, off));
            cn = fminf(cn, __shfl_xor(cn, off));
        }
        if (lhi == 0) {
            int loc = wc * 64 + n * 16 + l15;
            colp[wr][loc] = cp;
            coln[wr][loc] = cn;
        }
    }

    __syncthreads();

    if (tid < BM) {
        float pmv = fmaxf(fmaxf(rowp[0][tid], rowp[1][tid]), fmaxf(rowp[2][tid], rowp[3][tid]));
        float nmv = fminf(fminf(rown[0][tid], rown[1][tid]), fminf(rown[2][tid], rown[3][tid]));
        atomicMax(hp + i0 + tid, __float_as_uint(pmv));
        atomicMin(hn + i0 + tid, __float_as_uint(nmv));
    } else {
        int c = tid - BM;
        float pmv = fmaxf(colp[0][c], colp[1][c]);
        float nmv = fminf(coln[0][c], coln[1][c]);
        atomicMax(hp + j0 + c, __float_as_uint(pmv));
        atomicMin(hn + j0 + c, __float_as_uint(nmv));
    }
}

// ---------------- kernel 3: finalize ----------------
__global__ __launch_bounds__(1024) void final_k(const int* __restrict__ lab,
                                                const unsigned* __restrict__ hp,
                                                const unsigned* __restrict__ hn,
                                                float* __restrict__ out) {
    __shared__ int   cnt[NLBL];
    __shared__ float ssum[16];
    __shared__ int   scnt[16];
    int t = threadIdx.x;
    for (int i = t; i < NLBL; i += 1024) cnt[i] = 0;
    __syncthreads();
    for (int i = t; i < BATCH; i += 1024) atomicAdd(&cnt[lab[i]], 1);
    __syncthreads();

    float lsum = 0.0f;
    int   lcnt = 0;
    for (int i = t; i < BATCH; i += 1024) {
        int c = cnt[lab[i]];
        if ((c > 1) && (c < BATCH)) {
            float per = fmaxf(__uint_as_float(hp[i]) - __uint_as_float(hn[i]) + MARGIN, 0.0f);
            lsum += per;
            lcnt += 1;
        }
    }
    #pragma unroll
    for (int off = 1; off < 64; off <<= 1) {
        lsum += __shfl_xor(lsum, off);
        lcnt += __shfl_xor(lcnt, off);
    }
    int w = t >> 6;
    if ((t & 63) == 0) { ssum[w] = lsum; scnt[w] = lcnt; }
    __syncthreads();
    if (t == 0) {
        float s = 0.0f; int c2 = 0;
        #pragma unroll
        for (int i = 0; i < 16; ++i) { s += ssum[i]; c2 += scnt[i]; }
        out[0] = s / (float)max(c2, 1);
    }
}

// ---------------- launcher ----------------
extern "C" void kernel_launch(void* const* d_in, const int* in_sizes, int n_in,
                              void* d_out, int out_size, void* d_ws, size_t ws_size,
                              hipStream_t stream) {
    const float* emb = (const float*)d_in[0];
    const int*   lab = (const int*)d_in[1];

    char* base = (char*)d_ws;
    unsigned short* HiT = (unsigned short*)base;                      // 4 MB tiled
    unsigned* hp = (unsigned*)(base + (size_t)BATCH * DIM * 2);       // 16 KB
    unsigned* hn = hp + BATCH;                                        // 16 KB

    normalize_k<<<BATCH / 4, 256, 0, stream>>>(emb, HiT, hp, hn);
    mine_k<<<NPAIR, 512, 0, stream>>>(HiT, lab, hp, hn);
    final_k<<<1, 1024, 0, stream>>>(lab, hp, hn, (float*)d_out);
}

// Round 18
// 32.330 us; speedup vs baseline: 1.4535x; 1.4535x over previous
//
#include <hip/hip_runtime.h>
#include <hip/hip_bf16.h>

#define BATCH 4096
#define DIM   512
#define NLBL  512
#define BIGF  1e4f
#define MARGIN 1.0f

#define BM 128        // tile (rows = cols)
#define BK 64         // fp8 elems per K-step (8KB/tile -> 36KB LDS, 4 blocks/CU)
#define NT (BATCH/BM) // 32
#define NPAIR (NT*(NT+1)/2)  // 528
#define KITERS (DIM/BK)      // 8

// fp8 tiled layout: Hi8[tileR][panel][128][64] e4m3. One panel = 128*64B = 8KB
// contiguous. elem(r,k): tile r>>7, panel k>>6, byte (r&127)*64 + (k&63).
#define PANEL_B 8192

using f32x4  = __attribute__((ext_vector_type(4))) float;

// ---- compile-time pair table: supercell-compact enumeration of the triangle ----
struct PairTab { unsigned char bi[NPAIR]; unsigned char bj[NPAIR]; };
constexpr PairTab make_tab() {
    PairTab t{};
    int idx = 0;
    for (int BI = 0; BI < 8; ++BI)
        for (int BJ = BI; BJ < 8; ++BJ)
            for (int ii = 0; ii < 4; ++ii)
                for (int jj = 0; jj < 4; ++jj) {
                    int i = BI * 4 + ii, j = BJ * 4 + jj;
                    if (i <= j) {
                        t.bi[idx] = (unsigned char)i;
                        t.bj[idx] = (unsigned char)j;
                        ++idx;
                    }
                }
    return t;
}
__device__ constexpr PairTab PT = make_tab();

#define GLOAD16(gp, lp) \
    __builtin_amdgcn_global_load_lds((const __attribute__((address_space(1))) void*)(gp), \
                                     (__attribute__((address_space(3))) void*)(lp), 16, 0, 0)

// ---------------- kernel 1: L2-normalize -> fp8 e4m3 tiled (+ hp/hn init) ----------------
__global__ __launch_bounds__(256) void normalize_k(const float* __restrict__ emb,
                                                   unsigned char* __restrict__ Hi8,
                                                   unsigned* __restrict__ hp,
                                                   unsigned* __restrict__ hn) {
    int wave = threadIdx.x >> 6;
    int lane = threadIdx.x & 63;
    int row  = blockIdx.x * 4 + wave;
    const float4* src = (const float4*)(emb + (size_t)row * DIM);
    float4 v0 = src[lane * 2];
    float4 v1 = src[lane * 2 + 1];
    float ss = v0.x*v0.x + v0.y*v0.y + v0.z*v0.z + v0.w*v0.w
             + v1.x*v1.x + v1.y*v1.y + v1.z*v1.z + v1.w*v1.w;
    #pragma unroll
    for (int off = 1; off < 64; off <<= 1) ss += __shfl_xor(ss, off);
    float scale = 1.0f / fmaxf(sqrtf(ss), 1e-12f);
    // lane holds k = lane*8 .. +7
    int w0 = 0, w1 = 0;
    w0 = __builtin_amdgcn_cvt_pk_fp8_f32(v0.x * scale, v0.y * scale, w0, false);
    w0 = __builtin_amdgcn_cvt_pk_fp8_f32(v0.z * scale, v0.w * scale, w0, true);
    w1 = __builtin_amdgcn_cvt_pk_fp8_f32(v1.x * scale, v1.y * scale, w1, false);
    w1 = __builtin_amdgcn_cvt_pk_fp8_f32(v1.z * scale, v1.w * scale, w1, true);
    // tile r>>7, panel lane>>3, byte (r&127)*64 + (lane&7)*8
    size_t off = ((size_t)(row >> 7) * 8 + (lane >> 3)) * PANEL_B
               + (size_t)(row & 127) * 64 + (lane & 7) * 8;
    int2 o; o.x = w0; o.y = w1;
    *(int2*)(Hi8 + off) = o;
    if (lane == 0) {
        hp[row] = 0u;
        hn[row] = __float_as_uint(BIGF);
    }
}

// ---------------- kernel 2: fused fp8 MFMA sim + batch-hard mining ----------------
// R11 pipeline, fp8 panels: half the staging bytes (67.6 MB total), same 528
// blocks / 4 per CU. BK=64 => 2 MFMA K-slices per buffer, 8 K-steps.
__global__ __launch_bounds__(256, 4) void mine_k(const unsigned char* __restrict__ Hi8,
                                                 const int* __restrict__ lab,
                                                 unsigned* __restrict__ hp,
                                                 unsigned* __restrict__ hn) {
    __shared__ __attribute__((aligned(16))) unsigned char As[2][BM * BK]; // 16 KB
    __shared__ __attribute__((aligned(16))) unsigned char Bs[2][BM * BK]; // 16 KB
    __shared__ float rowp[2][BM], rown[2][BM], colp[2][BM], coln[2][BM];  // 4 KB

    int orig = (int)blockIdx.x;
    int p = (orig & 7) * (NPAIR / 8) + (orig >> 3);
    const int bi = PT.bi[p];
    const int bj = PT.bj[p];
    const int i0 = bi * BM;
    const int j0 = bj * BM;

    const int tid  = threadIdx.x;
    const int w    = tid >> 6;
    const int lane = tid & 63;
    const int wr   = w >> 1;
    const int wc   = w & 1;
    const int l15  = lane & 15;
    const int lhi  = lane >> 4;     // 0..3

    f32x4 acc[4][4] = {};
    const char* HiB = (const char*)Hi8;

    // stage one 128x64B fp8 panel pair; per wave 2 segs each (16 rows x 64B =
    // 1KB contiguous). Source 16B-chunk pre-swizzled: c16' = c16 ^ ((r>>1)&3).
    auto STAGE = [&](int buf, int t) {
        const size_t pa = ((size_t)bi * 8 + t) * PANEL_B;
        const size_t pb = ((size_t)bj * 8 + t) * PANEL_B;
        const int rrel = lane >> 2;               // 0..15
        #pragma unroll
        for (int q = 0; q < 2; ++q) {
            const int r   = w * 32 + q * 16 + rrel;
            const int c16 = (lane & 3) ^ ((r >> 1) & 3);
            const int soff = r * 64 + (c16 << 4);
            GLOAD16(HiB + pa + soff, (char*)As[buf] + (w * 32 + q * 16) * 64);
            GLOAD16(HiB + pb + soff, (char*)Bs[buf] + (w * 32 + q * 16) * 64);
        }
    };
    // LDS[r][c16] holds global[r][c16 ^ ((r>>1)&3)]. Fragment (kk,lhi) wants
    // logical c16 = kk*2 + (lhi>>1), half (lhi&1) -> conflict-free b64 reads.
    auto COMPUTE = [&](int buf) {
        #pragma unroll
        for (int kk = 0; kk < 2; ++kk) {
            long a[4], b[4];
            #pragma unroll
            for (int m = 0; m < 4; ++m) {
                int row = wr * 64 + m * 16 + l15;
                int cp  = (kk * 2 + (lhi >> 1)) ^ ((row >> 1) & 3);
                a[m] = *(const long*)((const char*)As[buf] + row * 64 + (cp << 4) + (lhi & 1) * 8);
            }
            #pragma unroll
            for (int n = 0; n < 4; ++n) {
                int row = wc * 64 + n * 16 + l15;
                int cp  = (kk * 2 + (lhi >> 1)) ^ ((row >> 1) & 3);
                b[n] = *(const long*)((const char*)Bs[buf] + row * 64 + (cp << 4) + (lhi & 1) * 8);
            }
            #pragma unroll
            for (int m = 0; m < 4; ++m)
                #pragma unroll
                for (int n = 0; n < 4; ++n)
                    acc[m][n] = __builtin_amdgcn_mfma_f32_16x16x32_fp8_fp8(a[m], b[n], acc[m][n], 0, 0, 0);
        }
    };

    // ---- counted-vmcnt double-buffer pipeline ----
    STAGE(0, 0);
    STAGE(1, 1);      // 8 loads in flight per wave
    #pragma unroll
    for (int t = 0; t < KITERS; ++t) {
        const int cur = t & 1;
        if (t < KITERS - 1) {
            asm volatile("s_waitcnt vmcnt(4)" ::: "memory");  // batch t landed; t+1 in flight
        } else {
            asm volatile("s_waitcnt vmcnt(0)" ::: "memory");
        }
        __builtin_amdgcn_sched_barrier(0);
        __builtin_amdgcn_s_barrier();      // buf cur fully written (all waves)
        COMPUTE(cur);
        __builtin_amdgcn_sched_barrier(0);
        __builtin_amdgcn_s_barrier();      // all waves done reading buf cur
        if (t + 2 < KITERS) STAGE(cur, t + 2);
    }

    // ---- labels ----
    int lj[4];
    #pragma unroll
    for (int n = 0; n < 4; ++n) lj[n] = lab[j0 + wc * 64 + n * 16 + l15];
    int li[16];
    #pragma unroll
    for (int m = 0; m < 4; ++m)
        #pragma unroll
        for (int r = 0; r < 4; ++r)
            li[m * 4 + r] = lab[i0 + wr * 64 + m * 16 + lhi * 4 + r];

    // ---- epilogue ----
    // C[i][j]: i = i0 + wr*64 + m*16 + lhi*4 + r ; j = j0 + wc*64 + n*16 + l15
    #pragma unroll
    for (int m = 0; m < 4; ++m) {
        #pragma unroll
        for (int r = 0; r < 4; ++r) {
            int i   = i0 + wr * 64 + m * 16 + lhi * 4 + r;
            int lir = li[m * 4 + r];
            float pm = 0.0f, nm = BIGF;
            #pragma unroll
            for (int n = 0; n < 4; ++n) {
                float dist = fmaxf(1.0f - acc[m][n][r], 0.0f);
                int j = j0 + wc * 64 + n * 16 + l15;
                if (lir == lj[n]) {
                    if (i != j) pm = fmaxf(pm, dist);
                } else {
                    nm = fminf(nm, dist);
                }
            }
            #pragma unroll
            for (int off = 1; off < 16; off <<= 1) {
                pm = fmaxf(pm, __shfl_xor(pm, off));
                nm = fminf(nm, __shfl_xor(nm, off));
            }
            if (l15 == 0) {
                int loc = wr * 64 + m * 16 + lhi * 4 + r;
                rowp[wc][loc] = pm;
                rown[wc][loc] = nm;
            }
        }
    }

    #pragma unroll
    for (int n = 0; n < 4; ++n) {
        int j   = j0 + wc * 64 + n * 16 + l15;
        int ljn = lj[n];
        float cp = 0.0f, cn = BIGF;
        #pragma unroll
        for (int m = 0; m < 4; ++m) {
            #pragma unroll
            for (int r = 0; r < 4; ++r) {
                float dist = fmaxf(1.0f - acc[m][n][r], 0.0f);
                int i = i0 + wr * 64 + m * 16 + lhi * 4 + r;
                if (li[m * 4 + r] == ljn) {
                    if (i != j) cp = fmaxf(cp, dist);
                } else {
                    cn = fminf(cn, dist);
                }
            }
        }
        #pragma unroll
        for (int off = 16; off < 64; off <<= 1) {
            cp = fmaxf(cp, __shfl_xor(cp, off));
            cn = fminf(cn, __shfl_xor(cn, off));
        }
        if (lhi == 0) {
            int loc = wc * 64 + n * 16 + l15;
            colp[wr][loc] = cp;
            coln[wr][loc] = cn;
        }
    }

    __syncthreads();

    if (tid < BM) {
        float pmv = fmaxf(rowp[0][tid], rowp[1][tid]);
        float nmv = fminf(rown[0][tid], rown[1][tid]);
        atomicMax(hp + i0 + tid, __float_as_uint(pmv));
        atomicMin(hn + i0 + tid, __float_as_uint(nmv));
    } else {
        int c = tid - BM;
        float pmv = fmaxf(colp[0][c], colp[1][c]);
        float nmv = fminf(coln[0][c], coln[1][c]);
        atomicMax(hp + j0 + c, __float_as_uint(pmv));
        atomicMin(hn + j0 + c, __float_as_uint(nmv));
    }
}

// ---------------- kernel 3: finalize ----------------
__global__ __launch_bounds__(1024) void final_k(const int* __restrict__ lab,
                                                const unsigned* __restrict__ hp,
                                                const unsigned* __restrict__ hn,
                                                float* __restrict__ out) {
    __shared__ int   cnt[NLBL];
    __shared__ float ssum[16];
    __shared__ int   scnt[16];
    int t = threadIdx.x;
    for (int i = t; i < NLBL; i += 1024) cnt[i] = 0;
    __syncthreads();
    for (int i = t; i < BATCH; i += 1024) atomicAdd(&cnt[lab[i]], 1);
    __syncthreads();

    float lsum = 0.0f;
    int   lcnt = 0;
    for (int i = t; i < BATCH; i += 1024) {
        int c = cnt[lab[i]];
        if ((c > 1) && (c < BATCH)) {
            float per = fmaxf(__uint_as_float(hp[i]) - __uint_as_float(hn[i]) + MARGIN, 0.0f);
            lsum += per;
            lcnt += 1;
        }
    }
    #pragma unroll
    for (int off = 1; off < 64; off <<= 1) {
        lsum += __shfl_xor(lsum, off);
        lcnt += __shfl_xor(lcnt, off);
    }
    int w = t >> 6;
    if ((t & 63) == 0) { ssum[w] = lsum; scnt[w] = lcnt; }
    __syncthreads();
    if (t == 0) {
        float s = 0.0f; int c2 = 0;
        #pragma unroll
        for (int i = 0; i < 16; ++i) { s += ssum[i]; c2 += scnt[i]; }
        out[0] = s / (float)max(c2, 1);
    }
}

// ---------------- launcher ----------------
extern "C" void kernel_launch(void* const* d_in, const int* in_sizes, int n_in,
                              void* d_out, int out_size, void* d_ws, size_t ws_size,
                              hipStream_t stream) {
    const float* emb = (const float*)d_in[0];
    const int*   lab = (const int*)d_in[1];

    char* base = (char*)d_ws;
    unsigned char* Hi8 = (unsigned char*)base;                        // 2 MB fp8 tiled
    unsigned* hp = (unsigned*)(base + (size_t)BATCH * DIM);           // 16 KB
    unsigned* hn = hp + BATCH;                                        // 16 KB

    normalize_k<<<BATCH / 4, 256, 0, stream>>>(emb, Hi8, hp, hn);
    mine_k<<<NPAIR, 256, 0, stream>>>(Hi8, lab, hp, hn);
    final_k<<<1, 1024, 0, stream>>>(lab, hp, hn, (float*)d_out);
}